// Round 1
// baseline (1449.727 us; speedup 1.0000x reference)
//
#include <hip/hip_runtime.h>
#include <stdint.h>

#define HIDDEN 4096
#define NHEADS 32
#define HD 128
#define SEQ 2048
#define NTOK 4096
#define QKVN 12288

typedef __attribute__((ext_vector_type(8))) short frag8;
typedef __attribute__((ext_vector_type(4))) float fl4;

__device__ __forceinline__ unsigned short f2b(float f) {
    unsigned u = __float_as_uint(f);
    return (unsigned short)((u + 0x7FFFu + ((u >> 16) & 1u)) >> 16);
}
__device__ __forceinline__ float b2f(unsigned short h) {
    return __uint_as_float(((unsigned)h) << 16);
}
// async global->LDS, 16B per lane. LDS dest is wave-uniform base + lane*16.
__device__ __forceinline__ void gl_lds16(const void* g, void* l) {
    __builtin_amdgcn_global_load_lds(
        (const __attribute__((address_space(1))) unsigned int*)(uintptr_t)g,
        (__attribute__((address_space(3))) unsigned int*)(uintptr_t)l,
        16, 0, 0);
}

// ---------------- fp32 -> bf16 conversion ----------------
__global__ void cvt_f32_bf16(const float* __restrict__ src,
                             unsigned short* __restrict__ dst, int n8) {
    int i = blockIdx.x * 256 + threadIdx.x;
    if (i >= n8) return;
    long e = (long)i * 8;
    fl4 a = *(const fl4*)(src + e);
    fl4 b = *(const fl4*)(src + e + 4);
    union { unsigned short us[8]; frag8 v; } o;
    o.us[0] = f2b(a[0]); o.us[1] = f2b(a[1]); o.us[2] = f2b(a[2]); o.us[3] = f2b(a[3]);
    o.us[4] = f2b(b[0]); o.us[5] = f2b(b[1]); o.us[6] = f2b(b[2]); o.us[7] = f2b(b[3]);
    *(frag8*)(dst + e) = o.v;
}

// ---------------- RoPE (in-place on q,k regions of proj) ----------------
__global__ void rope_kernel(unsigned short* __restrict__ proj,
                            const int* __restrict__ positions) {
    int tid = blockIdx.x * 256 + threadIdx.x;   // one thread per rotation pair
    int j  = tid & 63;
    int h  = (tid >> 6) & 31;
    int qk = (tid >> 11) & 1;
    int t  = tid >> 12;                          // token index 0..4095
    int pos = positions[t];
    float inv = powf(10000.0f, -(float)j * (1.0f / 64.0f));
    float fr = (float)pos * inv;
    float sv, cv;
    sincosf(fr, &sv, &cv);
    unsigned short* base = proj + (long)t * QKVN + qk * HIDDEN + h * HD;
    float x1 = b2f(base[j]);
    float x2 = b2f(base[j + 64]);
    base[j]      = f2b(x1 * cv - x2 * sv);
    base[j + 64] = f2b(x2 * cv + x1 * sv);
}

// ---------------- GEMM: C[M,N] = A[M,K] * B[N,K]^T (bf16 in, fp32 acc) --------
// m97 structure: 128x128 tile, BK=32, 4 waves (2x2), 4x4 16x16 subtiles/wave,
// global_load_lds width 16, XOR k-chunk swizzle to kill LDS bank conflicts.
template <int OUT_F32>
__global__ __launch_bounds__(256) void gemm_bt(
    const unsigned short* __restrict__ A,
    const unsigned short* __restrict__ B,
    void* __restrict__ Cv, int M, int N, int K) {
    __shared__ unsigned short As[128 * 32];
    __shared__ unsigned short Bs[128 * 32];
    const int tid  = threadIdx.x;
    const int lane = tid & 63;
    const int w    = tid >> 6;
    const long m0 = (long)blockIdx.y * 128;
    const long n0 = (long)blockIdx.x * 128;
    // staging: lane covers row srow (+0/+64), 8 bf16 (16B) chunk. LDS layout is
    // forced row-major (base + lane*16); the XOR permutes which logical k-chunk
    // lands in each physical slot: phys[r][c] = logical[r][c ^ ((r>>1)&3)].
    const int srow = w * 16 + (lane >> 2);
    const int pcol = (lane & 3) * 8;
    const int gcol = ((lane & 3) ^ ((lane >> 3) & 3)) * 8;
    const unsigned short* gA0 = A + (m0 + srow) * K + gcol;
    const unsigned short* gA1 = A + (m0 + 64 + srow) * K + gcol;
    const unsigned short* gB0 = B + (n0 + srow) * K + gcol;
    const unsigned short* gB1 = B + (n0 + 64 + srow) * K + gcol;
    unsigned short* lA0 = As + srow * 32 + pcol;
    unsigned short* lA1 = As + (64 + srow) * 32 + pcol;
    unsigned short* lB0 = Bs + srow * 32 + pcol;
    unsigned short* lB1 = Bs + (64 + srow) * 32 + pcol;

    const int wm = (w >> 1) * 64, wn = (w & 1) * 64;
    const int fr = lane & 15;
    const int quad = lane >> 4;
    const int axk = (quad ^ ((fr >> 1) & 3)) * 8;  // phys chunk for frag reads

    fl4 acc[4][4];
    fl4 z = {0.f, 0.f, 0.f, 0.f};
#pragma unroll
    for (int i = 0; i < 4; i++)
#pragma unroll
        for (int j = 0; j < 4; j++) acc[i][j] = z;

    for (int kt = 0; kt < K; kt += 32) {
        __syncthreads();
        gl_lds16(gA0 + kt, lA0);
        gl_lds16(gA1 + kt, lA1);
        gl_lds16(gB0 + kt, lB0);
        gl_lds16(gB1 + kt, lB1);
        __syncthreads();
        frag8 af[4], bf[4];
#pragma unroll
        for (int mi = 0; mi < 4; mi++)
            af[mi] = *(const frag8*)(As + (wm + mi * 16 + fr) * 32 + axk);
#pragma unroll
        for (int ni = 0; ni < 4; ni++)
            bf[ni] = *(const frag8*)(Bs + (wn + ni * 16 + fr) * 32 + axk);
#pragma unroll
        for (int mi = 0; mi < 4; mi++)
#pragma unroll
            for (int ni = 0; ni < 4; ni++)
                acc[mi][ni] = __builtin_amdgcn_mfma_f32_16x16x32_bf16(
                    af[mi], bf[ni], acc[mi][ni], 0, 0, 0);
    }
    const int q4 = quad * 4;
#pragma unroll
    for (int mi = 0; mi < 4; mi++)
#pragma unroll
        for (int ni = 0; ni < 4; ni++)
#pragma unroll
            for (int r = 0; r < 4; r++) {
                long row = m0 + wm + mi * 16 + q4 + r;
                long col = n0 + wn + ni * 16 + fr;
                float v = acc[mi][ni][r];
                if (OUT_F32)
                    ((float*)Cv)[row * N + col] = v;
                else
                    ((unsigned short*)Cv)[row * N + col] = f2b(v);
            }
}

// ---------------- causal flash attention ----------------
// block = (q-tile of 128) x head x batch; 4 waves, each owns 32 q rows.
// K-tile = 64 keys/iter. Q frags live in registers (loaded once from global).
__global__ __launch_bounds__(256, 2) void attn_kernel(
    const unsigned short* __restrict__ proj,   // [NTOK, 12288], rope'd
    unsigned short* __restrict__ out) {        // [NTOK, 4096]
    __shared__ unsigned short Ks[64 * 128];    // [k][d], XOR chunk swizzle
    __shared__ unsigned short Vt[128 * 80];    // [d][k], stride 80
    __shared__ unsigned short Ps[4][32 * 88];  // per-wave P, stride 88

    const int qt = (int)gridDim.x - 1 - (int)blockIdx.x;  // big tiles first
    const int h = blockIdx.y;
    const int b = blockIdx.z;
    const int tid = threadIdx.x, lane = tid & 63, w = tid >> 6;
    const int q0 = qt * 128;
    const int fr = lane & 15, quad = lane >> 4;
    const int fq = quad * 8;
    const long tokbase = (long)b * SEQ;
    const float scale = 0.08838834764831845f;  // 1/sqrt(128)
    fl4 z = {0.f, 0.f, 0.f, 0.f};

    // Q fragments (A-layout): rows q0 + w*32 + mi*16 + fr
    frag8 qf[2][4];
#pragma unroll
    for (int mi = 0; mi < 2; mi++)
#pragma unroll
        for (int kc = 0; kc < 4; kc++) {
            int qrow = q0 + w * 32 + mi * 16 + fr;
            qf[mi][kc] = *(const frag8*)(proj + (tokbase + qrow) * QKVN +
                                         h * HD + kc * 32 + fq);
        }

    fl4 o[2][8];
#pragma unroll
    for (int mi = 0; mi < 2; mi++)
#pragma unroll
        for (int n = 0; n < 8; n++) o[mi][n] = z;
    float m_i[2][4], l_i[2][4];
#pragma unroll
    for (int mi = 0; mi < 2; mi++)
#pragma unroll
        for (int r = 0; r < 4; r++) { m_i[mi][r] = -1e30f; l_i[mi][r] = 0.f; }

    // K staging: LDS row = c*16 + w*4 + (lane>>4); phys chunk lane&15;
    // XOR swizzle phys[r][c] = logical[r][c ^ (r&15)]
    const int ksrow = w * 4 + (lane >> 4);
    const int kphys = (lane & 15) * 8;
    const int kgcol = ((lane & 15) ^ ksrow) * 8;
    // V staging (transpose): thread -> (row=lane, dchunk=w*32)
    const int vrow = lane;
    const int vdc = w * 32;

    const int ktiles = (q0 + 128) / 64;
    for (int kt = 0; kt < ktiles; kt++) {
        const int k0 = kt * 64;
        __syncthreads();
#pragma unroll
        for (int c = 0; c < 4; c++) {
            long tok = tokbase + k0 + c * 16 + ksrow;
            gl_lds16(proj + tok * QKVN + HIDDEN + h * HD + kgcol,
                     Ks + (c * 16 + ksrow) * 128 + kphys);
        }
        {
            const unsigned short* vp =
                proj + (tokbase + k0 + vrow) * QKVN + 2 * HIDDEN + h * HD + vdc;
#pragma unroll
            for (int u = 0; u < 4; u++) {
                frag8 vv = *(const frag8*)(vp + u * 8);
#pragma unroll
                for (int e = 0; e < 8; e++)
                    Vt[(vdc + u * 8 + e) * 80 + vrow] = (unsigned short)vv[e];
            }
        }
        __syncthreads();

        // S = Q K^T
        fl4 sc[2][4];
#pragma unroll
        for (int kn = 0; kn < 4; kn++) {
            frag8 kf[4];
#pragma unroll
            for (int kc = 0; kc < 4; kc++)
                kf[kc] = *(const frag8*)(Ks + (kn * 16 + fr) * 128 +
                                         ((kc * 4 + quad) ^ fr) * 8);
#pragma unroll
            for (int mi = 0; mi < 2; mi++) {
                fl4 a = z;
#pragma unroll
                for (int kc = 0; kc < 4; kc++)
                    a = __builtin_amdgcn_mfma_f32_16x16x32_bf16(qf[mi][kc],
                                                                kf[kc], a, 0, 0, 0);
                sc[mi][kn] = a;
            }
        }
        // online softmax (rows = quad*4+r per C-layout)
#pragma unroll
        for (int mi = 0; mi < 2; mi++) {
#pragma unroll
            for (int r = 0; r < 4; r++) {
                int qrow = q0 + w * 32 + mi * 16 + quad * 4 + r;
                float sv4[4];
                float mx = -1e30f;
#pragma unroll
                for (int kn = 0; kn < 4; kn++) {
                    int kcol = k0 + kn * 16 + fr;
                    float s = sc[mi][kn][r] * scale;
                    s = (kcol <= qrow) ? s : -1e30f;
                    sv4[kn] = s;
                    mx = fmaxf(mx, s);
                }
#pragma unroll
                for (int off = 1; off < 16; off <<= 1)
                    mx = fmaxf(mx, __shfl_xor(mx, off, 64));
                float mold = m_i[mi][r];
                float mnew = fmaxf(mold, mx);
                float alpha = __expf(mold - mnew);
                float rsum = 0.f;
#pragma unroll
                for (int kn = 0; kn < 4; kn++) {
                    float p = __expf(sv4[kn] - mnew);
                    unsigned short pb = f2b(p);
                    Ps[w][(mi * 16 + quad * 4 + r) * 88 + kn * 16 + fr] = pb;
                    rsum += b2f(pb);
                }
#pragma unroll
                for (int off = 1; off < 16; off <<= 1)
                    rsum += __shfl_xor(rsum, off, 64);
                l_i[mi][r] = l_i[mi][r] * alpha + rsum;
                m_i[mi][r] = mnew;
#pragma unroll
                for (int n = 0; n < 8; n++) o[mi][n][r] *= alpha;
            }
        }
        // O += P V   (P round-trips LDS: C-layout -> A-layout; per-wave, no barrier)
        frag8 pf[2][2];
#pragma unroll
        for (int mi = 0; mi < 2; mi++)
#pragma unroll
            for (int kc = 0; kc < 2; kc++)
                pf[mi][kc] =
                    *(const frag8*)(Ps[w] + (mi * 16 + fr) * 88 + kc * 32 + fq);
#pragma unroll
        for (int n = 0; n < 8; n++) {
            frag8 vf0 = *(const frag8*)(Vt + (n * 16 + fr) * 80 + fq);
            frag8 vf1 = *(const frag8*)(Vt + (n * 16 + fr) * 80 + 32 + fq);
#pragma unroll
            for (int mi = 0; mi < 2; mi++) {
                o[mi][n] = __builtin_amdgcn_mfma_f32_16x16x32_bf16(pf[mi][0], vf0,
                                                                   o[mi][n], 0, 0, 0);
                o[mi][n] = __builtin_amdgcn_mfma_f32_16x16x32_bf16(pf[mi][1], vf1,
                                                                   o[mi][n], 0, 0, 0);
            }
        }
    }
    // epilogue: O / l -> out[tok][h*128 + d]
#pragma unroll
    for (int mi = 0; mi < 2; mi++)
#pragma unroll
        for (int n = 0; n < 8; n++)
#pragma unroll
            for (int r = 0; r < 4; r++) {
                int qrow = q0 + w * 32 + mi * 16 + quad * 4 + r;
                float val = o[mi][n][r] / l_i[mi][r];
                out[(tokbase + qrow) * HIDDEN + h * HD + n * 16 + fr] = f2b(val);
            }
}

extern "C" void kernel_launch(void* const* d_in, const int* in_sizes, int n_in,
                              void* d_out, int out_size, void* d_ws, size_t ws_size,
                              hipStream_t stream) {
    const float* hs = (const float*)d_in[0];   // [2,2048,4096]
    const int* pos  = (const int*)d_in[1];     // [2,2048]
    const float* wp = (const float*)d_in[2];   // [12288,4096]
    const float* wo = (const float*)d_in[3];   // [4096,4096]
    float* out = (float*)d_out;                // [2,2048,4096] fp32

    char* ws = (char*)d_ws;
    unsigned short* Xb    = (unsigned short*)ws;                 // 32 MB
    unsigned short* Wpb   = (unsigned short*)(ws + 33554432L);   // 96 MB
    unsigned short* proj  = (unsigned short*)(ws + 134217728L);  // 96 MB
    unsigned short* attnb = Wpb;  // reuse after gemm1
    unsigned short* Wob   = Xb;   // reuse after gemm1

    cvt_f32_bf16<<<(16777216 / 8) / 256, 256, 0, stream>>>(hs, Xb, 16777216 / 8);
    cvt_f32_bf16<<<(50331648 / 8) / 256, 256, 0, stream>>>(wp, Wpb, 50331648 / 8);
    gemm_bt<0><<<dim3(QKVN / 128, NTOK / 128), 256, 0, stream>>>(
        Xb, Wpb, (void*)proj, NTOK, QKVN, HIDDEN);
    rope_kernel<<<16777216 / 256, 256, 0, stream>>>(proj, pos);
    attn_kernel<<<dim3(SEQ / 128, NHEADS, 2), 256, 0, stream>>>(proj, attnb);
    cvt_f32_bf16<<<(16777216 / 8) / 256, 256, 0, stream>>>(wo, Wob, 16777216 / 8);
    gemm_bt<1><<<dim3(HIDDEN / 128, NTOK / 128), 256, 0, stream>>>(
        attnb, Wob, d_out, NTOK, HIDDEN, HIDDEN);
}